// Round 1
// baseline (399.417 us; speedup 1.0000x reference)
//
#include <hip/hip_runtime.h>
#include <stdint.h>

#define HH 512
#define WW 512
#define CIN 64
#define COUT 128
#define NB 4
#define CPAD 72   // LDS-padded channel dim (64 + 8) -> conflict-free ds_read_b128

typedef __bf16 bf16x8 __attribute__((ext_vector_type(8)));
typedef float f32x4 __attribute__((ext_vector_type(4)));

__device__ __forceinline__ unsigned short f2bf(float f) {
    union { float f; uint32_t u; } v; v.f = f;
    uint32_t u = v.u;
    u += 0x7fffu + ((u >> 16) & 1u);   // round-to-nearest-even
    return (unsigned short)(u >> 16);
}

// Wt2 layout: [(k>>3)][co][k&7] bf16, k = (ky*3+kx)*64 + ci, 576*128 elems
__global__ void wt_transform(const float* __restrict__ w, unsigned short* __restrict__ wt2) {
    int tid = blockIdx.x * 256 + threadIdx.x;
    if (tid >= COUT * 576) return;
    int co = tid / 576;
    int k  = tid - co * 576;
    int off = k >> 6;          // ky*3+kx
    int ci  = k & 63;
    int ky = off / 3;
    int kx = off - ky * 3;
    float val = w[((co * CIN + ci) * 3 + ky) * 3 + kx];
    wt2[(size_t)(k >> 3) * (COUT * 8) + co * 8 + (k & 7)] = f2bf(val);
}

// dense ws: [B][H][W][CIN] f32 (NHWC). One lane per (point, channel).
__global__ void scatter_kernel(const float* __restrict__ feat,
                               const int* __restrict__ coors,
                               float* __restrict__ dense, int npts) {
    int t = blockIdx.x * 256 + threadIdx.x;
    int p = t >> 6;
    int c = t & 63;
    if (p >= npts) return;
    int b = coors[p * 3 + 0];
    int y = coors[p * 3 + 1];
    int x = coors[p * 3 + 2];
    atomicAdd(&dense[(((size_t)b * HH + y) * WW + x) * CIN + c], feat[(size_t)p * CIN + c]);
}

// Per block: batch b, row y, 64 x-sites, all 128 co. 4 waves.
// GEMM: out[co][site] = sum_k Wt[co][k] * patch[k][site], k = 576.
__global__ __launch_bounds__(256) void conv_kernel(
        const float* __restrict__ dense,
        const unsigned short* __restrict__ wt2,
        float* __restrict__ out) {
    __shared__ __align__(16) unsigned short patch[3 * 66 * CPAD];

    const int bid = blockIdx.x;
    const int x0 = (bid & 7) * 64;
    const int y  = (bid >> 3) & 511;
    const int b  = bid >> 12;
    const int tid = threadIdx.x;

    // stage 3 rows x 66 cols x 64 ch, f32 -> bf16, zero-fill halo
    for (int i = tid; i < 3 * 66 * 16; i += 256) {
        int row = i / (66 * 16);
        int rem = i - row * (66 * 16);
        int col = rem >> 4;
        int c4  = rem & 15;
        int yy = y - 1 + row;
        int xx = x0 - 1 + col;
        float4 v = make_float4(0.f, 0.f, 0.f, 0.f);
        if ((unsigned)yy < HH && (unsigned)xx < WW) {
            v = *reinterpret_cast<const float4*>(
                &dense[(((size_t)b * HH + yy) * WW + xx) * CIN + (c4 << 2)]);
        }
        ushort4 s;
        s.x = f2bf(v.x); s.y = f2bf(v.y); s.z = f2bf(v.z); s.w = f2bf(v.w);
        *reinterpret_cast<ushort4*>(&patch[(row * 66 + col) * CPAD + (c4 << 2)]) = s;
    }
    __syncthreads();

    const int wave = tid >> 6;
    const int lane = tid & 63;
    const int lhi = lane >> 4;   // 0..3
    const int llo = lane & 15;
    const int co0 = wave * 32;   // wave owns co [co0, co0+32)

    f32x4 acc[2][4];
    #pragma unroll
    for (int m = 0; m < 2; ++m)
        #pragma unroll
        for (int n = 0; n < 4; ++n)
            acc[m][n] = (f32x4){0.f, 0.f, 0.f, 0.f};

    #pragma unroll
    for (int off = 0; off < 9; ++off) {
        const int ky = off / 3;
        const int kx = off - ky * 3;
        #pragma unroll
        for (int ch = 0; ch < 2; ++ch) {
            // A fragments (weights) from global; lane: co = co0+mt*16+llo, k = k0+lhi*8+e
            const size_t abase = (size_t)(off * 8 + ch * 4 + lhi) * (COUT * 8);
            bf16x8 a0 = *reinterpret_cast<const bf16x8*>(&wt2[abase + (co0 + llo) * 8]);
            bf16x8 a1 = *reinterpret_cast<const bf16x8*>(&wt2[abase + (co0 + 16 + llo) * 8]);
            #pragma unroll
            for (int nt = 0; nt < 4; ++nt) {
                // B fragment: lane holds k = k0+lhi*8+e (= ci contiguous), col = site
                bf16x8 bb = *reinterpret_cast<const bf16x8*>(
                    &patch[(ky * 66 + nt * 16 + llo + kx) * CPAD + ch * 32 + lhi * 8]);
                acc[0][nt] = __builtin_amdgcn_mfma_f32_16x16x32_bf16(a0, bb, acc[0][nt], 0, 0, 0);
                acc[1][nt] = __builtin_amdgcn_mfma_f32_16x16x32_bf16(a1, bb, acc[1][nt], 0, 0, 0);
            }
        }
    }

    // epilogue: D col = lane&15 -> x site, row = (lane>>4)*4+r -> co
    const size_t plane = (size_t)HH * WW;
    const size_t outbase = (size_t)b * COUT * plane + (size_t)y * WW + x0;
    #pragma unroll
    for (int m = 0; m < 2; ++m) {
        #pragma unroll
        for (int r = 0; r < 4; ++r) {
            int co = co0 + m * 16 + lhi * 4 + r;
            size_t rowbase = outbase + (size_t)co * plane;
            #pragma unroll
            for (int nt = 0; nt < 4; ++nt) {
                out[rowbase + nt * 16 + llo] = acc[m][nt][r];
            }
        }
    }
}

extern "C" void kernel_launch(void* const* d_in, const int* in_sizes, int n_in,
                              void* d_out, int out_size, void* d_ws, size_t ws_size,
                              hipStream_t stream) {
    const float* feat  = (const float*)d_in[0];
    const int*   coors = (const int*)d_in[1];
    const float* w     = (const float*)d_in[3];
    float* out = (float*)d_out;

    float* dense = (float*)d_ws;
    const size_t dense_bytes = (size_t)NB * HH * WW * CIN * sizeof(float); // 256 MB
    unsigned short* wt2 = (unsigned short*)((char*)d_ws + dense_bytes);

    const int npts = in_sizes[0] / CIN; // 200000

    hipMemsetAsync(d_ws, 0, dense_bytes, stream);

    hipLaunchKernelGGL(wt_transform, dim3((COUT * 576 + 255) / 256), dim3(256), 0, stream,
                       w, wt2);
    hipLaunchKernelGGL(scatter_kernel, dim3((npts * 64 + 255) / 256), dim3(256), 0, stream,
                       feat, coors, dense, npts);
    hipLaunchKernelGGL(conv_kernel, dim3(NB * HH * (WW / 64)), dim3(256), 0, stream,
                       dense, wt2, out);
}